// Round 6
// baseline (193.423 us; speedup 1.0000x reference)
//
#include <hip/hip_runtime.h>
#include <math.h>

#define Bb 256
#define Nn 4096
#define Cc 256
#define Rr 32
#define Kk 128
#define Lflat (Nn * Rr)          // 131072
#define LN2f 0.6931471805599453f
#define SKW 16                   // split-K factor for scorew MFMA

typedef unsigned short u16;
typedef __attribute__((ext_vector_type(8))) short short8b;  // 8 bf16
typedef __attribute__((ext_vector_type(4))) float f32x4;

typedef __attribute__((address_space(1))) const void* gas_t;
typedef __attribute__((address_space(3))) void* las_t;
__device__ __forceinline__ void gll16(const void* g, void* l) {
  __builtin_amdgcn_global_load_lds((gas_t)g, (las_t)l, 16, 0, 0);
}

__device__ inline u16 f2bf(float x) {            // RNE float->bf16
  unsigned u = __float_as_uint(x);
  unsigned r = (u + 0x7fffu + ((u >> 16) & 1u)) >> 16;
  return (u16)r;
}

// ---- monotone float<->uint mapping ----
__device__ inline unsigned f2u(float f) {
  unsigned b = __float_as_uint(f);
  return (b & 0x80000000u) ? ~b : (b | 0x80000000u);
}
__device__ inline float u2f(unsigned u) {
  unsigned b = (u & 0x80000000u) ? (u ^ 0x80000000u) : ~u;
  return __uint_as_float(b);
}

// ---------------- top-k via 8-bit radix select; fused scatter + norm_Mhat ----------
// Elements live in registers (16/thread). 4 digit passes, per-wave histograms.
__global__ __launch_bounds__(256) void topk_kernel(const float* __restrict__ A,
                                                   u16* __restrict__ S,
                                                   float* __restrict__ mhat) {
  int b = blockIdx.x, t = threadIdx.x;
  int lane = t & 63, wave = t >> 6;
  const float* row = A + (size_t)b * Nn;
  u16* Srow = S + (size_t)b * Nn;
  short8b z = {0, 0, 0, 0, 0, 0, 0, 0};
  *(short8b*)(Srow + t * 16) = z;                 // zero S row (ordered by barriers below)
  *(short8b*)(Srow + t * 16 + 8) = z;

  float f[16]; unsigned u[16];
#pragma unroll
  for (int j = 0; j < 4; ++j) {
    float4 v = ((const float4*)row)[j * 256 + t];
    f[j * 4 + 0] = v.x; f[j * 4 + 1] = v.y; f[j * 4 + 2] = v.z; f[j * 4 + 3] = v.w;
  }
#pragma unroll
  for (int j = 0; j < 16; ++j) u[j] = f2u(f[j]);

  __shared__ int hist[4][256];
  __shared__ int sufs[257];
  __shared__ int wtot[4];
  __shared__ int s_d, s_cg;
  __shared__ int s_eqidx[256];
  __shared__ int s_eqcnt;
  __shared__ float redQ[4];
  if (t == 0) s_eqcnt = 0;

  unsigned T = 0u;
  int cntG = 0;
#pragma unroll
  for (int p = 3; p >= 0; --p) {
    hist[0][t] = 0; hist[1][t] = 0; hist[2][t] = 0; hist[3][t] = 0;
    __syncthreads();
    unsigned mh = (p == 3) ? 0u : (0xFFFFFFFFu << (8 * (p + 1)));
    int* hw = hist[wave];
#pragma unroll
    for (int j = 0; j < 16; ++j)
      if (((u[j] ^ T) & mh) == 0) atomicAdd(&hw[(u[j] >> (8 * p)) & 255], 1);
    __syncthreads();
    int v = hist[0][t] + hist[1][t] + hist[2][t] + hist[3][t];
#pragma unroll
    for (int off = 1; off < 64; off <<= 1) {      // wave suffix-inclusive scan
      int tmp = __shfl_down(v, off, 64);
      if (lane + off < 64) v += tmp;
    }
    if (lane == 0) wtot[wave] = v;
    __syncthreads();
    for (int w2 = wave + 1; w2 < 4; ++w2) v += wtot[w2];
    sufs[t] = v;
    if (t == 0) sufs[256] = 0;
    __syncthreads();
    int nxt = sufs[t + 1];
    if ((cntG + v >= Kk) && (cntG + nxt < Kk)) { s_d = t; s_cg = cntG + nxt; }
    __syncthreads();
    T |= (unsigned)s_d << (8 * p);
    cntG = s_cg;
    __syncthreads();
  }
  // T = K-th largest (u-order); cntG = count(u > T) < K.
  float sq = 0.f;
#pragma unroll
  for (int j = 0; j < 16; ++j) {
    int idx = (j >> 2) * 1024 + t * 4 + (j & 3);
    if (u[j] > T) {
      Srow[idx] = f2bf(f[j]);
      sq += f[j] * f[j];
    } else if (u[j] == T) {
      int q2 = atomicAdd(&s_eqcnt, 1);
      if (q2 < 256) s_eqidx[q2] = idx;
    }
  }
#pragma unroll
  for (int off = 32; off; off >>= 1) sq += __shfl_xor(sq, off, 64);
  if (lane == 0) redQ[wave] = sq;
  __syncthreads();
  if (t == 0) {                                   // tie path: smallest indices (jax order)
    float tv = u2f(T);
    u16 tb = f2bf(tv);
    int need = Kk - cntG;
    int eq = min(s_eqcnt, 256);
    for (int s2 = 0; s2 < need; ++s2) {
      int best = 0x7fffffff, bi = 0;
      for (int jj = 0; jj < eq; ++jj)
        if (s_eqidx[jj] < best) { best = s_eqidx[jj]; bi = jj; }
      Srow[best] = tb;
      s_eqidx[bi] = 0x7fffffff;
    }
    mhat[b] = redQ[0] + redQ[1] + redQ[2] + redQ[3] + (float)need * tv * tv;
  }
}

// ---------------- u2t: U[c][n][r] fp32 -> UT[c][r][n] bf16, LDS-free ---------------
__global__ __launch_bounds__(256) void u2t_kernel(const float* __restrict__ U,
                                                  u16* __restrict__ UT) {
  int c = blockIdx.x, nb = blockIdx.y, t = threadIdx.x;
  int r = t & 31, nblk = t >> 5;                  // 8 n-chunks of 8
  const float* Uc = U + (size_t)c * Lflat;
  u16* UTc = UT + (size_t)c * Lflat;
  for (int it = 0; it < 8; ++it) {
    int n0 = nb * 512 + it * 64 + nblk * 8;
    union { short8b v; u16 s[8]; } pk;
#pragma unroll
    for (int i = 0; i < 8; ++i)
      pk.s[i] = f2bf(Uc[(size_t)(n0 + i) * Rr + r]);   // lanes 0-31: consecutive floats
    *(short8b*)(UTc + (size_t)r * Nn + n0) = pk.v;
  }
}

// ---------------- score_w via bf16 MFMA, softplus fused in staging -----------------
__global__ __launch_bounds__(256) void scorew_mfma_kernel(const float* __restrict__ Ag,
                                                          const float* __restrict__ W,
                                                          float* __restrict__ SWp) {
  int ct = blockIdx.x, mt = blockIdx.y, ks = blockIdx.z;
  int t = threadIdx.x;
  int lane = t & 63, wave = t >> 6;
  int lo = lane & 15, hi = lane >> 4;
  int wr = wave >> 1, wc = wave & 1;
  __shared__ __align__(16) u16 As[64 * 64];
  __shared__ __align__(16) u16 Ws[64 * 64];
  f32x4 acc[2][2];
#pragma unroll
  for (int m = 0; m < 2; ++m)
#pragma unroll
    for (int n = 0; n < 2; ++n) acc[m][n] = (f32x4){0.f, 0.f, 0.f, 0.f};
  int kbase = ks * (Nn / SKW);
  for (int k0 = 0; k0 < Nn / SKW; k0 += 64) {
    for (int s = t; s < 1024; s += 256) {
      int panel = s >> 9;
      int sl = s & 511;
      int row = sl >> 3, q = sl & 7;
      union { short8b v; u16 u[8]; } pk;
      if (panel == 0) {
        const float* src = Ag + (size_t)(mt * 64 + row) * Nn + kbase + k0 + q * 8;
        float4 f0 = *(const float4*)src, f1 = *(const float4*)(src + 4);
        pk.u[0] = f2bf(f0.x); pk.u[1] = f2bf(f0.y); pk.u[2] = f2bf(f0.z); pk.u[3] = f2bf(f0.w);
        pk.u[4] = f2bf(f1.x); pk.u[5] = f2bf(f1.y); pk.u[6] = f2bf(f1.z); pk.u[7] = f2bf(f1.w);
        *(short8b*)(&As[row * 64 + ((q ^ (row & 7)) << 3)]) = pk.v;
      } else {
        const float* src = W + (size_t)(ct * 64 + row) * Nn + kbase + k0 + q * 8;
        float4 f0 = *(const float4*)src, f1 = *(const float4*)(src + 4);
        float w[8] = {f0.x, f0.y, f0.z, f0.w, f1.x, f1.y, f1.z, f1.w};
#pragma unroll
        for (int j = 0; j < 8; ++j)
          pk.u[j] = f2bf(fmaxf(w[j], 0.f) + log1pf(expf(-fabsf(w[j]))) - LN2f);
        *(short8b*)(&Ws[row * 64 + ((q ^ (row & 7)) << 3)]) = pk.v;
      }
    }
    __syncthreads();
#pragma unroll
    for (int kf = 0; kf < 2; ++kf) {
      int q = kf * 4 + hi;
      short8b af[2], bf[2];
#pragma unroll
      for (int m = 0; m < 2; ++m) {
        int row = wr * 32 + m * 16 + lo;
        af[m] = *(const short8b*)(&As[row * 64 + ((q ^ (row & 7)) << 3)]);
      }
#pragma unroll
      for (int n = 0; n < 2; ++n) {
        int row = wc * 32 + n * 16 + lo;
        bf[n] = *(const short8b*)(&Ws[row * 64 + ((q ^ (row & 7)) << 3)]);
      }
#pragma unroll
      for (int m = 0; m < 2; ++m)
#pragma unroll
        for (int n = 0; n < 2; ++n)
          acc[m][n] = __builtin_amdgcn_mfma_f32_16x16x32_bf16(af[m], bf[n], acc[m][n], 0, 0, 0);
    }
    __syncthreads();
  }
  float* o = SWp + (size_t)ks * (Bb * Cc);
#pragma unroll
  for (int m = 0; m < 2; ++m)
#pragma unroll
    for (int n = 0; n < 2; ++n)
#pragma unroll
      for (int r = 0; r < 4; ++r) {
        int b = mt * 64 + wr * 32 + m * 16 + hi * 4 + r;
        int c = ct * 64 + wc * 32 + n * 16 + lo;
        o[(size_t)b * Cc + c] = acc[m][n][r];
      }
}

// ---------------- Gram from bf16 UT via global_load_lds ----------------
__global__ __launch_bounds__(256) void gram_bf16_kernel(const u16* __restrict__ UT,
                                                        float* __restrict__ Gpart,
                                                        int kch) {
  int bx = blockIdx.x;
  int tile = bx % 3, chunk = bx / 3;
  int ti = (tile == 2) ? 1 : 0;
  int tj = (tile == 0) ? 0 : 1;
  bool diag = (tile != 1);
  int t = threadIdx.x, lane = t & 63, wave = t >> 6;
  int lo = lane & 15, hi = lane >> 4;
  int wr = wave >> 1, wc = wave & 1;
  __shared__ __align__(16) u16 lp[2][128 * 64];
  f32x4 acc[4][4];
#pragma unroll
  for (int m = 0; m < 4; ++m)
#pragma unroll
    for (int n = 0; n < 4; ++n) acc[m][n] = (f32x4){0.f, 0.f, 0.f, 0.f};
  int lrow = lane >> 3;
  int lchunk8 = ((lane & 7) ^ lrow) * 8;          // source-side swizzle (rule #21)
  size_t kbase = (size_t)chunk * kch;
  for (int k0 = 0; k0 < kch; k0 += 64) {
    size_t kg = kbase + k0;
#pragma unroll
    for (int q = 0; q < 4; ++q) {
      int row = wave * 32 + q * 8;
      gll16(UT + (size_t)(ti * 128 + row + lrow) * Lflat + kg + lchunk8, &lp[0][row * 64]);
    }
    if (!diag) {
#pragma unroll
      for (int q = 0; q < 4; ++q) {
        int row = wave * 32 + q * 8;
        gll16(UT + (size_t)(tj * 128 + row + lrow) * Lflat + kg + lchunk8, &lp[1][row * 64]);
      }
    }
    __syncthreads();
#pragma unroll
    for (int ks = 0; ks < 2; ++ks) {
      short8b af[4], bfv[4];
#pragma unroll
      for (int m = 0; m < 4; ++m) {
        int row = wr * 64 + m * 16 + lo;
        af[m] = *(const short8b*)(&lp[0][row * 64 + (((ks * 4 + hi) ^ (row & 7)) << 3)]);
      }
      const u16* pb = diag ? lp[0] : lp[1];
#pragma unroll
      for (int n = 0; n < 4; ++n) {
        int row = wc * 64 + n * 16 + lo;
        bfv[n] = *(const short8b*)(&pb[row * 64 + (((ks * 4 + hi) ^ (row & 7)) << 3)]);
      }
#pragma unroll
      for (int m = 0; m < 4; ++m)
#pragma unroll
        for (int n = 0; n < 4; ++n)
          acc[m][n] = __builtin_amdgcn_mfma_f32_16x16x32_bf16(af[m], bfv[n], acc[m][n], 0, 0, 0);
    }
    __syncthreads();
  }
  float* gp = Gpart + (size_t)bx * 16384;
#pragma unroll
  for (int m = 0; m < 4; ++m)
#pragma unroll
    for (int n = 0; n < 4; ++n)
#pragma unroll
      for (int r = 0; r < 4; ++r) {
        int row = wr * 64 + m * 16 + hi * 4 + r;
        int col = wc * 64 + n * 16 + lo;
        gp[row * 128 + col] = acc[m][n][r];
      }
}

// ---------------- Gram via bf16 MFMA from fp32 U (fallback) ----------
__global__ __launch_bounds__(256) void gram_mfma_kernel(const float* __restrict__ U,
                                                        float* __restrict__ Gpart,
                                                        int kch) {
  int bx = blockIdx.x;
  int tile = bx % 3;
  int chunk = bx / 3;
  int ti = (tile == 2) ? 1 : 0;
  int tj = (tile == 0) ? 0 : 1;
  bool diag = (tile != 1);
  int t = threadIdx.x;
  int lane = t & 63, wave = t >> 6;
  int lo = lane & 15, hi = lane >> 4;
  int wr = wave >> 1, wc = wave & 1;
  __shared__ __align__(16) u16 lp[2][128 * 64];
  size_t kbase = (size_t)chunk * kch;
  f32x4 acc[4][4];
#pragma unroll
  for (int m = 0; m < 4; ++m)
#pragma unroll
    for (int n = 0; n < 4; ++n) acc[m][n] = (f32x4){0.f, 0.f, 0.f, 0.f};
  int nslots = diag ? 1024 : 2048;
  for (int k0 = 0; k0 < kch; k0 += 64) {
    for (int s = t; s < nslots; s += 256) {
      int panel = s >> 10;
      int sl = s & 1023;
      int row = sl >> 3, q = sl & 7;
      int grow = (panel ? tj : ti) * 128 + row;
      const float* src = U + (size_t)grow * Lflat + kbase + k0 + q * 8;
      float4 f0 = *(const float4*)src;
      float4 f1 = *(const float4*)(src + 4);
      union { short8b v; u16 u[8]; } pk;
      pk.u[0] = f2bf(f0.x); pk.u[1] = f2bf(f0.y); pk.u[2] = f2bf(f0.z); pk.u[3] = f2bf(f0.w);
      pk.u[4] = f2bf(f1.x); pk.u[5] = f2bf(f1.y); pk.u[6] = f2bf(f1.z); pk.u[7] = f2bf(f1.w);
      *(short8b*)(&lp[panel][row * 64 + ((q ^ (row & 7)) << 3)]) = pk.v;
    }
    __syncthreads();
#pragma unroll
    for (int ks = 0; ks < 2; ++ks) {
      short8b af[4], bfv[4];
#pragma unroll
      for (int m = 0; m < 4; ++m) {
        int row = wr * 64 + m * 16 + lo;
        af[m] = *(const short8b*)(&lp[0][row * 64 + (((ks * 4 + hi) ^ (row & 7)) << 3)]);
      }
      const u16* pb = diag ? lp[0] : lp[1];
#pragma unroll
      for (int n = 0; n < 4; ++n) {
        int row = wc * 64 + n * 16 + lo;
        bfv[n] = *(const short8b*)(&pb[row * 64 + (((ks * 4 + hi) ^ (row & 7)) << 3)]);
      }
#pragma unroll
      for (int m = 0; m < 4; ++m)
#pragma unroll
        for (int n = 0; n < 4; ++n)
          acc[m][n] = __builtin_amdgcn_mfma_f32_16x16x32_bf16(af[m], bfv[n], acc[m][n], 0, 0, 0);
    }
    __syncthreads();
  }
  float* gp = Gpart + (size_t)bx * 16384;
#pragma unroll
  for (int m = 0; m < 4; ++m)
#pragma unroll
    for (int n = 0; n < 4; ++n)
#pragma unroll
      for (int r = 0; r < 4; ++r) {
        int row = wr * 64 + m * 16 + hi * 4 + r;
        int col = wc * 64 + n * 16 + lo;
        gp[row * 128 + col] = acc[m][n][r];
      }
}

__global__ __launch_bounds__(256) void gram_reduce_kernel(const float* __restrict__ Gpart,
                                                          float* __restrict__ G,
                                                          int nchunks) {
  int tile = blockIdx.x % 3, seg = blockIdx.x / 3;
  int ti = (tile == 2) ? 1 : 0;
  int tj = (tile == 0) ? 0 : 1;
  int e = seg * 1024 + threadIdx.x * 4;
  float4 s = {0.f, 0.f, 0.f, 0.f};
  for (int ch = 0; ch < nchunks; ++ch) {
    float4 v = *(const float4*)(Gpart + ((size_t)(ch * 3 + tile)) * 16384 + e);
    s.x += v.x; s.y += v.y; s.z += v.z; s.w += v.w;
  }
  int row = e >> 7, col = e & 127;
  int gi = ti * 128 + row, gj = tj * 128 + col;
  G[gi * Cc + gj + 0] = s.x;
  G[gi * Cc + gj + 1] = s.y;
  G[gi * Cc + gj + 2] = s.z;
  G[gi * Cc + gj + 3] = s.w;
  if (tile == 1) {
    G[(gj + 0) * Cc + gi] = s.x;
    G[(gj + 1) * Cc + gi] = s.y;
    G[(gj + 2) * Cc + gi] = s.z;
    G[(gj + 3) * Cc + gi] = s.w;
  }
}

// ---------------- Au = S @ UT^T : bf16 GEMM (M=256, N=8192, K=4096) ----------------
__global__ __launch_bounds__(256) void au_gemm_kernel(const u16* __restrict__ S,
                                                      const u16* __restrict__ UT,
                                                      float* __restrict__ Au,
                                                      float* __restrict__ SC) {
  int jt = blockIdx.x, bt = blockIdx.y;
  int t = threadIdx.x, lane = t & 63, wave = t >> 6;
  int lo = lane & 15, hi = lane >> 4;
  int wr = wave >> 1, wc = wave & 1;
  __shared__ __align__(16) u16 Sa[128 * 64];
  __shared__ __align__(16) u16 Ub[64 * 64];
  f32x4 acc[4][2];
#pragma unroll
  for (int m = 0; m < 4; ++m)
#pragma unroll
    for (int n = 0; n < 2; ++n) acc[m][n] = (f32x4){0.f, 0.f, 0.f, 0.f};
  int lrow = lane >> 3;
  int lchunk8 = ((lane & 7) ^ lrow) * 8;
  for (int k0 = 0; k0 < Nn; k0 += 64) {
#pragma unroll
    for (int q = 0; q < 4; ++q) {
      int row = wave * 32 + q * 8;
      gll16(S + (size_t)(bt * 128 + row + lrow) * Nn + k0 + lchunk8, &Sa[row * 64]);
    }
#pragma unroll
    for (int q = 0; q < 2; ++q) {
      int row = wave * 16 + q * 8;
      gll16(UT + (size_t)(jt * 64 + row + lrow) * Nn + k0 + lchunk8, &Ub[row * 64]);
    }
    __syncthreads();
#pragma unroll
    for (int ks = 0; ks < 2; ++ks) {
      int q = ks * 4 + hi;
      short8b af[4], bfv[2];
#pragma unroll
      for (int m = 0; m < 4; ++m) {
        int r = wr * 64 + m * 16 + lo;
        af[m] = *(const short8b*)(&Sa[r * 64 + ((q ^ (r & 7)) << 3)]);
      }
#pragma unroll
      for (int n = 0; n < 2; ++n) {
        int r = wc * 32 + n * 16 + lo;
        bfv[n] = *(const short8b*)(&Ub[r * 64 + ((q ^ (r & 7)) << 3)]);
      }
#pragma unroll
      for (int m = 0; m < 4; ++m)
#pragma unroll
        for (int n = 0; n < 2; ++n)
          acc[m][n] = __builtin_amdgcn_mfma_f32_16x16x32_bf16(af[m], bfv[n], acc[m][n], 0, 0, 0);
    }
    __syncthreads();
  }
  int c = jt * 2 + wc;
#pragma unroll
  for (int m = 0; m < 4; ++m)
#pragma unroll
    for (int rr = 0; rr < 4; ++rr) {
      int b = bt * 128 + wr * 64 + m * 16 + hi * 4 + rr;
      float a0 = acc[m][0][rr], a1 = acc[m][1][rr];
      Au[((size_t)b * Cc + c) * Rr + lo]      = a0;
      Au[((size_t)b * Cc + c) * Rr + 16 + lo] = a1;
      float sq = a0 * a0 + a1 * a1;
      sq += __shfl_xor(sq, 1, 64);
      sq += __shfl_xor(sq, 2, 64);
      sq += __shfl_xor(sq, 4, 64);
      sq += __shfl_xor(sq, 8, 64);
      if (lo == 0) SC[(size_t)b * Cc + c] = sq * (1.f / (Kk * Rr));
    }
}

// ---------------- Au fallback (fp32 U, in-kernel transpose) ----------------
__global__ __launch_bounds__(256) void au_mfma_kernel(const float* __restrict__ U,
                                                      const u16* __restrict__ S,
                                                      float* __restrict__ Au,
                                                      float* __restrict__ SC) {
  int c = blockIdx.x, mb = blockIdx.y;
  int t = threadIdx.x;
  int lane = t & 63, wave = t >> 6;
  int lo = lane & 15, hi = lane >> 4;
  __shared__ __align__(16) u16 Ss[128 * 64];
  __shared__ __align__(16) u16 Us[32 * 64];
  f32x4 acc[2][2];
#pragma unroll
  for (int m = 0; m < 2; ++m)
#pragma unroll
    for (int n = 0; n < 2; ++n) acc[m][n] = (f32x4){0.f, 0.f, 0.f, 0.f};
  const float* Uc = U + (size_t)c * Lflat;
  for (int k0 = 0; k0 < Nn; k0 += 64) {
    for (int s = t; s < 1024; s += 256) {
      int row = s >> 3, q = s & 7;
      short8b v = *(const short8b*)(S + (size_t)(mb * 128 + row) * Nn + k0 + q * 8);
      *(short8b*)(&Ss[row * 64 + ((q ^ (row & 7)) << 3)]) = v;
    }
    for (int s = t; s < 512; s += 256) {
      int kk = s >> 3, rq = s & 7;
      float4 f = *(const float4*)(Uc + (size_t)(k0 + kk) * Rr + rq * 4);
      float fv[4] = {f.x, f.y, f.z, f.w};
#pragma unroll
      for (int j = 0; j < 4; ++j) {
        int r = rq * 4 + j;
        Us[r * 64 + (((kk >> 3) ^ (r & 7)) << 3) + (kk & 7)] = f2bf(fv[j]);
      }
    }
    __syncthreads();
#pragma unroll
    for (int kf = 0; kf < 2; ++kf) {
      int q = kf * 4 + hi;
      short8b af[2], bf[2];
#pragma unroll
      for (int m = 0; m < 2; ++m) {
        int row = wave * 32 + m * 16 + lo;
        af[m] = *(const short8b*)(&Ss[row * 64 + ((q ^ (row & 7)) << 3)]);
      }
#pragma unroll
      for (int n = 0; n < 2; ++n) {
        int row = n * 16 + lo;
        bf[n] = *(const short8b*)(&Us[row * 64 + ((q ^ (row & 7)) << 3)]);
      }
#pragma unroll
      for (int m = 0; m < 2; ++m)
#pragma unroll
        for (int n = 0; n < 2; ++n)
          acc[m][n] = __builtin_amdgcn_mfma_f32_16x16x32_bf16(af[m], bf[n], acc[m][n], 0, 0, 0);
    }
    __syncthreads();
  }
#pragma unroll
  for (int m = 0; m < 2; ++m) {
#pragma unroll
    for (int r = 0; r < 4; ++r) {
      int b = mb * 128 + wave * 32 + m * 16 + hi * 4 + r;
#pragma unroll
      for (int n = 0; n < 2; ++n) {
        int rr = n * 16 + lo;
        Au[((size_t)b * Cc + c) * Rr + rr] = acc[m][n][r];
      }
      float sq = acc[m][0][r] * acc[m][0][r] + acc[m][1][r] * acc[m][1][r];
      sq += __shfl_xor(sq, 1, 64);
      sq += __shfl_xor(sq, 2, 64);
      sq += __shfl_xor(sq, 4, 64);
      sq += __shfl_xor(sq, 8, 64);
      if (lo == 0) SC[(size_t)b * Cc + c] = sq * (1.f / (Kk * Rr));
    }
  }
}

// ---------------- fused: match scores + softmax + residual ----------------
__global__ __launch_bounds__(256) void softfin_kernel(const float* __restrict__ SWp,
                                                      const float* __restrict__ SC,
                                                      const float* __restrict__ span_t,
                                                      const float* __restrict__ PS,
                                                      const float* __restrict__ G,
                                                      const float* __restrict__ Au,
                                                      const float* __restrict__ mhat,
                                                      float* __restrict__ out) {
  int b = blockIdx.x, t = threadIdx.x;
  int lane = t & 63, wave = t >> 6;
  __shared__ float redM[4], redS[4], redA[4];
  __shared__ float sb[Cc];
  __shared__ float au2[8][32];
  float span_norm = fminf(fmaxf(span_t[b] * (1.f / 20.f), 0.f), 1.f);
  float psn = 1.f / (1.f + expf(-PS[t]));
  float m = 0.f;
#pragma unroll
  for (int kc = 0; kc < SKW; ++kc) m += SWp[(size_t)kc * (Bb * Cc) + b * Cc + t];
  m += SC[b * Cc + t] - 0.3f * fabsf(span_norm - psn);
  float mx = m;
#pragma unroll
  for (int off = 32; off; off >>= 1) mx = fmaxf(mx, __shfl_xor(mx, off, 64));
  if (lane == 0) redM[wave] = mx;
  __syncthreads();
  mx = fmaxf(fmaxf(redM[0], redM[1]), fmaxf(redM[2], redM[3]));
  float e = expf(m - mx);
  float s = e;
#pragma unroll
  for (int off = 32; off; off >>= 1) s += __shfl_xor(s, off, 64);
  if (lane == 0) redS[wave] = s;
  __syncthreads();
  s = redS[0] + redS[1] + redS[2] + redS[3];
  float beta_t = e / s;
  sb[t] = beta_t;
  __syncthreads();
  // recon partial: w_t = sum_c beta_c G[c,t] (coalesced row-major reads)
  float w = 0.f;
#pragma unroll 8
  for (int c = 0; c < Cc; ++c) w = fmaf(sb[c], G[c * Cc + t], w);
  float pr = beta_t * w;
  // cross partials
  int r = t & 31, g = t >> 5;
  float pp = 0.f;
#pragma unroll 8
  for (int cc = 0; cc < 32; ++cc) {
    int c = cc * 8 + g;
    pp = fmaf(sb[c], Au[((size_t)b * Cc + c) * Rr + r], pp);
  }
  au2[g][r] = pp;
  float x = pr;
#pragma unroll
  for (int off = 32; off; off >>= 1) x += __shfl_xor(x, off, 64);
  if (lane == 0) redA[wave] = x;
  __syncthreads();
  float recon = (redA[0] + redA[1] + redA[2] + redA[3]) * (1.f / 4096.f);
  float cr = 0.f;
  if (t < 32) {
    float a2 = au2[0][t] + au2[1][t] + au2[2][t] + au2[3][t]
             + au2[4][t] + au2[5][t] + au2[6][t] + au2[7][t];
    cr = a2 * a2;
  }
#pragma unroll
  for (int off = 16; off; off >>= 1) cr += __shfl_xor(cr, off, 64);
  if (t == 0) {
    cr *= (1.f / 4096.f);
    float res = mhat[b] * (1.f / 128.f) - 2.f * cr + recon;
    out[b] = fminf(fmaxf(res, 0.f), 10000.f);
  }
}

extern "C" void kernel_launch(void* const* d_in, const int* in_sizes, int n_in,
                              void* d_out, int out_size, void* d_ws, size_t ws_size,
                              hipStream_t stream) {
  const float* A      = (const float*)d_in[0];
  const float* span_t = (const float*)d_in[1];
  const float* W      = (const float*)d_in[2];
  const float* U      = (const float*)d_in[3];
  const float* PS     = (const float*)d_in[4];
  float* out = (float*)d_out;

  char* p = (char*)d_ws;
  float* mhat = (float*)p; p += (size_t)Bb * 4;
  float* SWp  = (float*)p; p += (size_t)SKW * Bb * Cc * 4;
  float* SC   = (float*)p; p += (size_t)Bb * Cc * 4;
  float* G    = (float*)p; p += (size_t)Cc * Cc * 4;
  u16*   S    = (u16*)p;   p += (size_t)Bb * Nn * 2;
  float* Au   = (float*)p; p += (size_t)Bb * Cc * Rr * 4;
  size_t fixed = (size_t)(p - (char*)d_ws);
  size_t UTsz = (size_t)Cc * Lflat * 2;                       // 67 MB
  bool planA = ws_size >= fixed + UTsz + (size_t)3 * 8 * 16384 * 4;

  topk_kernel<<<dim3(Bb), dim3(256), 0, stream>>>(A, S, mhat);
  scorew_mfma_kernel<<<dim3(4, 4, SKW), dim3(256), 0, stream>>>(A, W, SWp);

  if (planA) {
    u16* UT = (u16*)p; p += UTsz;
    size_t used = fixed + UTsz;
    int nchunks = 64;
    while (nchunks > 8 && used + (size_t)(3 * nchunks) * 16384 * 4 > ws_size) nchunks >>= 1;
    float* Gpart = (float*)p;
    u2t_kernel<<<dim3(Cc, 8), dim3(256), 0, stream>>>(U, UT);
    gram_bf16_kernel<<<dim3(3 * nchunks), dim3(256), 0, stream>>>(UT, Gpart, Lflat / nchunks);
    gram_reduce_kernel<<<dim3(48), dim3(256), 0, stream>>>(Gpart, G, nchunks);
    au_gemm_kernel<<<dim3(128, 2), dim3(256), 0, stream>>>(S, UT, Au, SC);
  } else {
    int nchunks = 64;
    while (nchunks > 8 && fixed + (size_t)(3 * nchunks) * 16384 * 4 > ws_size) nchunks >>= 1;
    float* Gpart = (float*)p;
    gram_mfma_kernel<<<dim3(3 * nchunks), dim3(256), 0, stream>>>(U, Gpart, Lflat / nchunks);
    gram_reduce_kernel<<<dim3(48), dim3(256), 0, stream>>>(Gpart, G, nchunks);
    au_mfma_kernel<<<dim3(Cc, 2), dim3(256), 0, stream>>>(U, S, Au, SC);
  }

  softfin_kernel<<<dim3(Bb), dim3(256), 0, stream>>>(SWp, SC, span_t, PS, G, Au, mhat, out);
}

// Round 7
// 193.185 us; speedup vs baseline: 1.0012x; 1.0012x over previous
//
#include <hip/hip_runtime.h>
#include <math.h>

#define Bb 256
#define Nn 4096
#define Cc 256
#define Rr 32
#define Kk 128
#define Lflat (Nn * Rr)          // 131072
#define LN2f 0.6931471805599453f
#define SKW 16                   // split-K factor for scorew MFMA

typedef unsigned short u16;
typedef __attribute__((ext_vector_type(8))) short short8b;  // 8 bf16
typedef __attribute__((ext_vector_type(4))) float f32x4;

typedef __attribute__((address_space(1))) const void* gas_t;
typedef __attribute__((address_space(3))) void* las_t;
__device__ __forceinline__ void gll16(const void* g, void* l) {
  __builtin_amdgcn_global_load_lds((gas_t)g, (las_t)l, 16, 0, 0);
}

__device__ inline u16 f2bf(float x) {            // RNE float->bf16
  unsigned u = __float_as_uint(x);
  unsigned r = (u + 0x7fffu + ((u >> 16) & 1u)) >> 16;
  return (u16)r;
}

// ---- monotone float<->uint mapping ----
__device__ inline unsigned f2u(float f) {
  unsigned b = __float_as_uint(f);
  return (b & 0x80000000u) ? ~b : (b | 0x80000000u);
}
__device__ inline float u2f(unsigned u) {
  unsigned b = (u & 0x80000000u) ? (u ^ 0x80000000u) : ~u;
  return __uint_as_float(b);
}

// ---------------- top-k via 8-bit radix select; fused scatter + norm_Mhat ----------
// Elements live in registers (16/thread). 4 digit passes, per-wave histograms.
__global__ __launch_bounds__(256) void topk_kernel(const float* __restrict__ A,
                                                   u16* __restrict__ S,
                                                   float* __restrict__ mhat) {
  int b = blockIdx.x, t = threadIdx.x;
  int lane = t & 63, wave = t >> 6;
  const float* row = A + (size_t)b * Nn;
  u16* Srow = S + (size_t)b * Nn;
  short8b z = {0, 0, 0, 0, 0, 0, 0, 0};
  *(short8b*)(Srow + t * 16) = z;                 // zero S row (ordered by barriers below)
  *(short8b*)(Srow + t * 16 + 8) = z;

  float f[16]; unsigned u[16];
#pragma unroll
  for (int j = 0; j < 4; ++j) {
    float4 v = ((const float4*)row)[j * 256 + t];
    f[j * 4 + 0] = v.x; f[j * 4 + 1] = v.y; f[j * 4 + 2] = v.z; f[j * 4 + 3] = v.w;
  }
#pragma unroll
  for (int j = 0; j < 16; ++j) u[j] = f2u(f[j]);

  __shared__ int hist[4][256];
  __shared__ int sufs[257];
  __shared__ int wtot[4];
  __shared__ int s_d, s_cg;
  __shared__ int s_eqidx[256];
  __shared__ int s_eqcnt;
  __shared__ float redQ[4];
  if (t == 0) s_eqcnt = 0;

  unsigned T = 0u;
  int cntG = 0;
#pragma unroll
  for (int p = 3; p >= 0; --p) {
    hist[0][t] = 0; hist[1][t] = 0; hist[2][t] = 0; hist[3][t] = 0;
    __syncthreads();
    unsigned mh = (p == 3) ? 0u : (0xFFFFFFFFu << (8 * (p + 1)));
    int* hw = hist[wave];
#pragma unroll
    for (int j = 0; j < 16; ++j)
      if (((u[j] ^ T) & mh) == 0) atomicAdd(&hw[(u[j] >> (8 * p)) & 255], 1);
    __syncthreads();
    int v = hist[0][t] + hist[1][t] + hist[2][t] + hist[3][t];
#pragma unroll
    for (int off = 1; off < 64; off <<= 1) {      // wave suffix-inclusive scan
      int tmp = __shfl_down(v, off, 64);
      if (lane + off < 64) v += tmp;
    }
    if (lane == 0) wtot[wave] = v;
    __syncthreads();
    for (int w2 = wave + 1; w2 < 4; ++w2) v += wtot[w2];
    sufs[t] = v;
    if (t == 0) sufs[256] = 0;
    __syncthreads();
    int nxt = sufs[t + 1];
    if ((cntG + v >= Kk) && (cntG + nxt < Kk)) { s_d = t; s_cg = cntG + nxt; }
    __syncthreads();
    T |= (unsigned)s_d << (8 * p);
    cntG = s_cg;
    __syncthreads();
  }
  // T = K-th largest (u-order); cntG = count(u > T) < K.
  float sq = 0.f;
#pragma unroll
  for (int j = 0; j < 16; ++j) {
    int idx = (j >> 2) * 1024 + t * 4 + (j & 3);
    if (u[j] > T) {
      Srow[idx] = f2bf(f[j]);
      sq += f[j] * f[j];
    } else if (u[j] == T) {
      int q2 = atomicAdd(&s_eqcnt, 1);
      if (q2 < 256) s_eqidx[q2] = idx;
    }
  }
#pragma unroll
  for (int off = 32; off; off >>= 1) sq += __shfl_xor(sq, off, 64);
  if (lane == 0) redQ[wave] = sq;
  __syncthreads();
  if (t == 0) {                                   // tie path: smallest indices (jax order)
    float tv = u2f(T);
    u16 tb = f2bf(tv);
    int need = Kk - cntG;
    int eq = min(s_eqcnt, 256);
    for (int s2 = 0; s2 < need; ++s2) {
      int best = 0x7fffffff, bi = 0;
      for (int jj = 0; jj < eq; ++jj)
        if (s_eqidx[jj] < best) { best = s_eqidx[jj]; bi = jj; }
      Srow[best] = tb;
      s_eqidx[bi] = 0x7fffffff;
    }
    mhat[b] = redQ[0] + redQ[1] + redQ[2] + redQ[3] + (float)need * tv * tv;
  }
}

// ---------------- u2t: U[c][n][r] fp32 -> UT[c][r][n] bf16, LDS-free ---------------
__global__ __launch_bounds__(256) void u2t_kernel(const float* __restrict__ U,
                                                  u16* __restrict__ UT) {
  int c = blockIdx.x, nb = blockIdx.y, t = threadIdx.x;
  int r = t & 31, nblk = t >> 5;                  // 8 n-chunks of 8
  const float* Uc = U + (size_t)c * Lflat;
  u16* UTc = UT + (size_t)c * Lflat;
  for (int it = 0; it < 8; ++it) {
    int n0 = nb * 512 + it * 64 + nblk * 8;
    union { short8b v; u16 s[8]; } pk;
#pragma unroll
    for (int i = 0; i < 8; ++i)
      pk.s[i] = f2bf(Uc[(size_t)(n0 + i) * Rr + r]);   // lanes 0-31: consecutive floats
    *(short8b*)(UTc + (size_t)r * Nn + n0) = pk.v;
  }
}

// ---------------- score_w via bf16 MFMA, softplus fused in staging -----------------
__global__ __launch_bounds__(256) void scorew_mfma_kernel(const float* __restrict__ Ag,
                                                          const float* __restrict__ W,
                                                          float* __restrict__ SWp) {
  int ct = blockIdx.x, mt = blockIdx.y, ks = blockIdx.z;
  int t = threadIdx.x;
  int lane = t & 63, wave = t >> 6;
  int lo = lane & 15, hi = lane >> 4;
  int wr = wave >> 1, wc = wave & 1;
  __shared__ __align__(16) u16 As[64 * 64];
  __shared__ __align__(16) u16 Ws[64 * 64];
  f32x4 acc[2][2];
#pragma unroll
  for (int m = 0; m < 2; ++m)
#pragma unroll
    for (int n = 0; n < 2; ++n) acc[m][n] = (f32x4){0.f, 0.f, 0.f, 0.f};
  int kbase = ks * (Nn / SKW);
  for (int k0 = 0; k0 < Nn / SKW; k0 += 64) {
    for (int s = t; s < 1024; s += 256) {
      int panel = s >> 9;
      int sl = s & 511;
      int row = sl >> 3, q = sl & 7;
      union { short8b v; u16 u[8]; } pk;
      if (panel == 0) {
        const float* src = Ag + (size_t)(mt * 64 + row) * Nn + kbase + k0 + q * 8;
        float4 f0 = *(const float4*)src, f1 = *(const float4*)(src + 4);
        pk.u[0] = f2bf(f0.x); pk.u[1] = f2bf(f0.y); pk.u[2] = f2bf(f0.z); pk.u[3] = f2bf(f0.w);
        pk.u[4] = f2bf(f1.x); pk.u[5] = f2bf(f1.y); pk.u[6] = f2bf(f1.z); pk.u[7] = f2bf(f1.w);
        *(short8b*)(&As[row * 64 + ((q ^ (row & 7)) << 3)]) = pk.v;
      } else {
        const float* src = W + (size_t)(ct * 64 + row) * Nn + kbase + k0 + q * 8;
        float4 f0 = *(const float4*)src, f1 = *(const float4*)(src + 4);
        float w[8] = {f0.x, f0.y, f0.z, f0.w, f1.x, f1.y, f1.z, f1.w};
#pragma unroll
        for (int j = 0; j < 8; ++j)
          pk.u[j] = f2bf(fmaxf(w[j], 0.f) + log1pf(expf(-fabsf(w[j]))) - LN2f);
        *(short8b*)(&Ws[row * 64 + ((q ^ (row & 7)) << 3)]) = pk.v;
      }
    }
    __syncthreads();
#pragma unroll
    for (int kf = 0; kf < 2; ++kf) {
      int q = kf * 4 + hi;
      short8b af[2], bf[2];
#pragma unroll
      for (int m = 0; m < 2; ++m) {
        int row = wr * 32 + m * 16 + lo;
        af[m] = *(const short8b*)(&As[row * 64 + ((q ^ (row & 7)) << 3)]);
      }
#pragma unroll
      for (int n = 0; n < 2; ++n) {
        int row = wc * 32 + n * 16 + lo;
        bf[n] = *(const short8b*)(&Ws[row * 64 + ((q ^ (row & 7)) << 3)]);
      }
#pragma unroll
      for (int m = 0; m < 2; ++m)
#pragma unroll
        for (int n = 0; n < 2; ++n)
          acc[m][n] = __builtin_amdgcn_mfma_f32_16x16x32_bf16(af[m], bf[n], acc[m][n], 0, 0, 0);
    }
    __syncthreads();
  }
  float* o = SWp + (size_t)ks * (Bb * Cc);
#pragma unroll
  for (int m = 0; m < 2; ++m)
#pragma unroll
    for (int n = 0; n < 2; ++n)
#pragma unroll
      for (int r = 0; r < 4; ++r) {
        int b = mt * 64 + wr * 32 + m * 16 + hi * 4 + r;
        int c = ct * 64 + wc * 32 + n * 16 + lo;
        o[(size_t)b * Cc + c] = acc[m][n][r];
      }
}

// ---------------- Gram from bf16 UT via global_load_lds ----------------
__global__ __launch_bounds__(256) void gram_bf16_kernel(const u16* __restrict__ UT,
                                                        float* __restrict__ Gpart,
                                                        int kch) {
  int bx = blockIdx.x;
  int tile = bx % 3, chunk = bx / 3;
  int ti = (tile == 2) ? 1 : 0;
  int tj = (tile == 0) ? 0 : 1;
  bool diag = (tile != 1);
  int t = threadIdx.x, lane = t & 63, wave = t >> 6;
  int lo = lane & 15, hi = lane >> 4;
  int wr = wave >> 1, wc = wave & 1;
  __shared__ __align__(16) u16 lp[2][128 * 64];
  f32x4 acc[4][4];
#pragma unroll
  for (int m = 0; m < 4; ++m)
#pragma unroll
    for (int n = 0; n < 4; ++n) acc[m][n] = (f32x4){0.f, 0.f, 0.f, 0.f};
  int lrow = lane >> 3;
  int lchunk8 = ((lane & 7) ^ lrow) * 8;          // source-side swizzle (rule #21)
  size_t kbase = (size_t)chunk * kch;
  for (int k0 = 0; k0 < kch; k0 += 64) {
    size_t kg = kbase + k0;
#pragma unroll
    for (int q = 0; q < 4; ++q) {
      int row = wave * 32 + q * 8;
      gll16(UT + (size_t)(ti * 128 + row + lrow) * Lflat + kg + lchunk8, &lp[0][row * 64]);
    }
    if (!diag) {
#pragma unroll
      for (int q = 0; q < 4; ++q) {
        int row = wave * 32 + q * 8;
        gll16(UT + (size_t)(tj * 128 + row + lrow) * Lflat + kg + lchunk8, &lp[1][row * 64]);
      }
    }
    __syncthreads();
#pragma unroll
    for (int ks = 0; ks < 2; ++ks) {
      short8b af[4], bfv[4];
#pragma unroll
      for (int m = 0; m < 4; ++m) {
        int row = wr * 64 + m * 16 + lo;
        af[m] = *(const short8b*)(&lp[0][row * 64 + (((ks * 4 + hi) ^ (row & 7)) << 3)]);
      }
      const u16* pb = diag ? lp[0] : lp[1];
#pragma unroll
      for (int n = 0; n < 4; ++n) {
        int row = wc * 64 + n * 16 + lo;
        bfv[n] = *(const short8b*)(&pb[row * 64 + (((ks * 4 + hi) ^ (row & 7)) << 3)]);
      }
#pragma unroll
      for (int m = 0; m < 4; ++m)
#pragma unroll
        for (int n = 0; n < 4; ++n)
          acc[m][n] = __builtin_amdgcn_mfma_f32_16x16x32_bf16(af[m], bfv[n], acc[m][n], 0, 0, 0);
    }
    __syncthreads();
  }
  float* gp = Gpart + (size_t)bx * 16384;
#pragma unroll
  for (int m = 0; m < 4; ++m)
#pragma unroll
    for (int n = 0; n < 4; ++n)
#pragma unroll
      for (int r = 0; r < 4; ++r) {
        int row = wr * 64 + m * 16 + hi * 4 + r;
        int col = wc * 64 + n * 16 + lo;
        gp[row * 128 + col] = acc[m][n][r];
      }
}

// ---------------- Gram via bf16 MFMA from fp32 U (fallback) ----------
__global__ __launch_bounds__(256) void gram_mfma_kernel(const float* __restrict__ U,
                                                        float* __restrict__ Gpart,
                                                        int kch) {
  int bx = blockIdx.x;
  int tile = bx % 3;
  int chunk = bx / 3;
  int ti = (tile == 2) ? 1 : 0;
  int tj = (tile == 0) ? 0 : 1;
  bool diag = (tile != 1);
  int t = threadIdx.x;
  int lane = t & 63, wave = t >> 6;
  int lo = lane & 15, hi = lane >> 4;
  int wr = wave >> 1, wc = wave & 1;
  __shared__ __align__(16) u16 lp[2][128 * 64];
  size_t kbase = (size_t)chunk * kch;
  f32x4 acc[4][4];
#pragma unroll
  for (int m = 0; m < 4; ++m)
#pragma unroll
    for (int n = 0; n < 4; ++n) acc[m][n] = (f32x4){0.f, 0.f, 0.f, 0.f};
  int nslots = diag ? 1024 : 2048;
  for (int k0 = 0; k0 < kch; k0 += 64) {
    for (int s = t; s < nslots; s += 256) {
      int panel = s >> 10;
      int sl = s & 1023;
      int row = sl >> 3, q = sl & 7;
      int grow = (panel ? tj : ti) * 128 + row;
      const float* src = U + (size_t)grow * Lflat + kbase + k0 + q * 8;
      float4 f0 = *(const float4*)src;
      float4 f1 = *(const float4*)(src + 4);
      union { short8b v; u16 u[8]; } pk;
      pk.u[0] = f2bf(f0.x); pk.u[1] = f2bf(f0.y); pk.u[2] = f2bf(f0.z); pk.u[3] = f2bf(f0.w);
      pk.u[4] = f2bf(f1.x); pk.u[5] = f2bf(f1.y); pk.u[6] = f2bf(f1.z); pk.u[7] = f2bf(f1.w);
      *(short8b*)(&lp[panel][row * 64 + ((q ^ (row & 7)) << 3)]) = pk.v;
    }
    __syncthreads();
#pragma unroll
    for (int ks = 0; ks < 2; ++ks) {
      short8b af[4], bfv[4];
#pragma unroll
      for (int m = 0; m < 4; ++m) {
        int row = wr * 64 + m * 16 + lo;
        af[m] = *(const short8b*)(&lp[0][row * 64 + (((ks * 4 + hi) ^ (row & 7)) << 3)]);
      }
      const u16* pb = diag ? lp[0] : lp[1];
#pragma unroll
      for (int n = 0; n < 4; ++n) {
        int row = wc * 64 + n * 16 + lo;
        bfv[n] = *(const short8b*)(&pb[row * 64 + (((ks * 4 + hi) ^ (row & 7)) << 3)]);
      }
#pragma unroll
      for (int m = 0; m < 4; ++m)
#pragma unroll
        for (int n = 0; n < 4; ++n)
          acc[m][n] = __builtin_amdgcn_mfma_f32_16x16x32_bf16(af[m], bfv[n], acc[m][n], 0, 0, 0);
    }
    __syncthreads();
  }
  float* gp = Gpart + (size_t)bx * 16384;
#pragma unroll
  for (int m = 0; m < 4; ++m)
#pragma unroll
    for (int n = 0; n < 4; ++n)
#pragma unroll
      for (int r = 0; r < 4; ++r) {
        int row = wr * 64 + m * 16 + hi * 4 + r;
        int col = wc * 64 + n * 16 + lo;
        gp[row * 128 + col] = acc[m][n][r];
      }
}

__global__ __launch_bounds__(256) void gram_reduce_kernel(const float* __restrict__ Gpart,
                                                          float* __restrict__ G,
                                                          int nchunks) {
  int tile = blockIdx.x % 3, seg = blockIdx.x / 3;
  int ti = (tile == 2) ? 1 : 0;
  int tj = (tile == 0) ? 0 : 1;
  int e = seg * 1024 + threadIdx.x * 4;
  float4 s = {0.f, 0.f, 0.f, 0.f};
  for (int ch = 0; ch < nchunks; ++ch) {
    float4 v = *(const float4*)(Gpart + ((size_t)(ch * 3 + tile)) * 16384 + e);
    s.x += v.x; s.y += v.y; s.z += v.z; s.w += v.w;
  }
  int row = e >> 7, col = e & 127;
  int gi = ti * 128 + row, gj = tj * 128 + col;
  G[gi * Cc + gj + 0] = s.x;
  G[gi * Cc + gj + 1] = s.y;
  G[gi * Cc + gj + 2] = s.z;
  G[gi * Cc + gj + 3] = s.w;
  if (tile == 1) {
    G[(gj + 0) * Cc + gi] = s.x;
    G[(gj + 1) * Cc + gi] = s.y;
    G[(gj + 2) * Cc + gi] = s.z;
    G[(gj + 3) * Cc + gi] = s.w;
  }
}

// ---------------- Au = S @ UT^T : bf16 GEMM (M=256, N=8192, K=4096) ----------------
__global__ __launch_bounds__(256) void au_gemm_kernel(const u16* __restrict__ S,
                                                      const u16* __restrict__ UT,
                                                      float* __restrict__ Au,
                                                      float* __restrict__ SC) {
  int jt = blockIdx.x, bt = blockIdx.y;
  int t = threadIdx.x, lane = t & 63, wave = t >> 6;
  int lo = lane & 15, hi = lane >> 4;
  int wr = wave >> 1, wc = wave & 1;
  __shared__ __align__(16) u16 Sa[128 * 64];
  __shared__ __align__(16) u16 Ub[64 * 64];
  f32x4 acc[4][2];
#pragma unroll
  for (int m = 0; m < 4; ++m)
#pragma unroll
    for (int n = 0; n < 2; ++n) acc[m][n] = (f32x4){0.f, 0.f, 0.f, 0.f};
  int lrow = lane >> 3;
  int lchunk8 = ((lane & 7) ^ lrow) * 8;
  for (int k0 = 0; k0 < Nn; k0 += 64) {
#pragma unroll
    for (int q = 0; q < 4; ++q) {
      int row = wave * 32 + q * 8;
      gll16(S + (size_t)(bt * 128 + row + lrow) * Nn + k0 + lchunk8, &Sa[row * 64]);
    }
#pragma unroll
    for (int q = 0; q < 2; ++q) {
      int row = wave * 16 + q * 8;
      gll16(UT + (size_t)(jt * 64 + row + lrow) * Nn + k0 + lchunk8, &Ub[row * 64]);
    }
    __syncthreads();
#pragma unroll
    for (int ks = 0; ks < 2; ++ks) {
      int q = ks * 4 + hi;
      short8b af[4], bfv[2];
#pragma unroll
      for (int m = 0; m < 4; ++m) {
        int r = wr * 64 + m * 16 + lo;
        af[m] = *(const short8b*)(&Sa[r * 64 + ((q ^ (r & 7)) << 3)]);
      }
#pragma unroll
      for (int n = 0; n < 2; ++n) {
        int r = wc * 32 + n * 16 + lo;
        bfv[n] = *(const short8b*)(&Ub[r * 64 + ((q ^ (r & 7)) << 3)]);
      }
#pragma unroll
      for (int m = 0; m < 4; ++m)
#pragma unroll
        for (int n = 0; n < 2; ++n)
          acc[m][n] = __builtin_amdgcn_mfma_f32_16x16x32_bf16(af[m], bfv[n], acc[m][n], 0, 0, 0);
    }
    __syncthreads();
  }
  int c = jt * 2 + wc;
#pragma unroll
  for (int m = 0; m < 4; ++m)
#pragma unroll
    for (int rr = 0; rr < 4; ++rr) {
      int b = bt * 128 + wr * 64 + m * 16 + hi * 4 + rr;
      float a0 = acc[m][0][rr], a1 = acc[m][1][rr];
      Au[((size_t)b * Cc + c) * Rr + lo]      = a0;
      Au[((size_t)b * Cc + c) * Rr + 16 + lo] = a1;
      float sq = a0 * a0 + a1 * a1;
      sq += __shfl_xor(sq, 1, 64);
      sq += __shfl_xor(sq, 2, 64);
      sq += __shfl_xor(sq, 4, 64);
      sq += __shfl_xor(sq, 8, 64);
      if (lo == 0) SC[(size_t)b * Cc + c] = sq * (1.f / (Kk * Rr));
    }
}

// ---------------- Au fallback (fp32 U, in-kernel transpose) ----------------
__global__ __launch_bounds__(256) void au_mfma_kernel(const float* __restrict__ U,
                                                      const u16* __restrict__ S,
                                                      float* __restrict__ Au,
                                                      float* __restrict__ SC) {
  int c = blockIdx.x, mb = blockIdx.y;
  int t = threadIdx.x;
  int lane = t & 63, wave = t >> 6;
  int lo = lane & 15, hi = lane >> 4;
  __shared__ __align__(16) u16 Ss[128 * 64];
  __shared__ __align__(16) u16 Us[32 * 64];
  f32x4 acc[2][2];
#pragma unroll
  for (int m = 0; m < 2; ++m)
#pragma unroll
    for (int n = 0; n < 2; ++n) acc[m][n] = (f32x4){0.f, 0.f, 0.f, 0.f};
  const float* Uc = U + (size_t)c * Lflat;
  for (int k0 = 0; k0 < Nn; k0 += 64) {
    for (int s = t; s < 1024; s += 256) {
      int row = s >> 3, q = s & 7;
      short8b v = *(const short8b*)(S + (size_t)(mb * 128 + row) * Nn + k0 + q * 8);
      *(short8b*)(&Ss[row * 64 + ((q ^ (row & 7)) << 3)]) = v;
    }
    for (int s = t; s < 512; s += 256) {
      int kk = s >> 3, rq = s & 7;
      float4 f = *(const float4*)(Uc + (size_t)(k0 + kk) * Rr + rq * 4);
      float fv[4] = {f.x, f.y, f.z, f.w};
#pragma unroll
      for (int j = 0; j < 4; ++j) {
        int r = rq * 4 + j;
        Us[r * 64 + (((kk >> 3) ^ (r & 7)) << 3) + (kk & 7)] = f2bf(fv[j]);
      }
    }
    __syncthreads();
#pragma unroll
    for (int kf = 0; kf < 2; ++kf) {
      int q = kf * 4 + hi;
      short8b af[2], bf[2];
#pragma unroll
      for (int m = 0; m < 2; ++m) {
        int row = wave * 32 + m * 16 + lo;
        af[m] = *(const short8b*)(&Ss[row * 64 + ((q ^ (row & 7)) << 3)]);
      }
#pragma unroll
      for (int n = 0; n < 2; ++n) {
        int row = n * 16 + lo;
        bf[n] = *(const short8b*)(&Us[row * 64 + ((q ^ (row & 7)) << 3)]);
      }
#pragma unroll
      for (int m = 0; m < 2; ++m)
#pragma unroll
        for (int n = 0; n < 2; ++n)
          acc[m][n] = __builtin_amdgcn_mfma_f32_16x16x32_bf16(af[m], bf[n], acc[m][n], 0, 0, 0);
    }
    __syncthreads();
  }
#pragma unroll
  for (int m = 0; m < 2; ++m) {
#pragma unroll
    for (int r = 0; r < 4; ++r) {
      int b = mb * 128 + wave * 32 + m * 16 + hi * 4 + r;
#pragma unroll
      for (int n = 0; n < 2; ++n) {
        int rr = n * 16 + lo;
        Au[((size_t)b * Cc + c) * Rr + rr] = acc[m][n][r];
      }
      float sq = acc[m][0][r] * acc[m][0][r] + acc[m][1][r] * acc[m][1][r];
      sq += __shfl_xor(sq, 1, 64);
      sq += __shfl_xor(sq, 2, 64);
      sq += __shfl_xor(sq, 4, 64);
      sq += __shfl_xor(sq, 8, 64);
      if (lo == 0) SC[(size_t)b * Cc + c] = sq * (1.f / (Kk * Rr));
    }
  }
}

// ---------------- fused: match scores + softmax + residual ----------------
__global__ __launch_bounds__(256) void softfin_kernel(const float* __restrict__ SWp,
                                                      const float* __restrict__ SC,
                                                      const float* __restrict__ span_t,
                                                      const float* __restrict__ PS,
                                                      const float* __restrict__ G,
                                                      const float* __restrict__ Au,
                                                      const float* __restrict__ mhat,
                                                      float* __restrict__ out) {
  int b = blockIdx.x, t = threadIdx.x;
  int lane = t & 63, wave = t >> 6;
  __shared__ float redM[4], redS[4], redA[4];
  __shared__ float sb[Cc];
  __shared__ float au2[8][32];
  float span_norm = fminf(fmaxf(span_t[b] * (1.f / 20.f), 0.f), 1.f);
  float psn = 1.f / (1.f + expf(-PS[t]));
  float m = 0.f;
#pragma unroll
  for (int kc = 0; kc < SKW; ++kc) m += SWp[(size_t)kc * (Bb * Cc) + b * Cc + t];
  m += SC[b * Cc + t] - 0.3f * fabsf(span_norm - psn);
  float mx = m;
#pragma unroll
  for (int off = 32; off; off >>= 1) mx = fmaxf(mx, __shfl_xor(mx, off, 64));
  if (lane == 0) redM[wave] = mx;
  __syncthreads();
  mx = fmaxf(fmaxf(redM[0], redM[1]), fmaxf(redM[2], redM[3]));
  float e = expf(m - mx);
  float s = e;
#pragma unroll
  for (int off = 32; off; off >>= 1) s += __shfl_xor(s, off, 64);
  if (lane == 0) redS[wave] = s;
  __syncthreads();
  s = redS[0] + redS[1] + redS[2] + redS[3];
  float beta_t = e / s;
  sb[t] = beta_t;
  __syncthreads();
  // recon partial: w_t = sum_c beta_c G[c,t] (coalesced row-major reads)
  float w = 0.f;
#pragma unroll 8
  for (int c = 0; c < Cc; ++c) w = fmaf(sb[c], G[c * Cc + t], w);
  float pr = beta_t * w;
  // cross partials
  int r = t & 31, g = t >> 5;
  float pp = 0.f;
#pragma unroll 8
  for (int cc = 0; cc < 32; ++cc) {
    int c = cc * 8 + g;
    pp = fmaf(sb[c], Au[((size_t)b * Cc + c) * Rr + r], pp);
  }
  au2[g][r] = pp;
  float x = pr;
#pragma unroll
  for (int off = 32; off; off >>= 1) x += __shfl_xor(x, off, 64);
  if (lane == 0) redA[wave] = x;
  __syncthreads();
  float recon = (redA[0] + redA[1] + redA[2] + redA[3]) * (1.f / 4096.f);
  float cr = 0.f;
  if (t < 32) {
    float a2 = au2[0][t] + au2[1][t] + au2[2][t] + au2[3][t]
             + au2[4][t] + au2[5][t] + au2[6][t] + au2[7][t];
    cr = a2 * a2;
  }
#pragma unroll
  for (int off = 16; off; off >>= 1) cr += __shfl_xor(cr, off, 64);
  if (t == 0) {
    cr *= (1.f / 4096.f);
    float res = mhat[b] * (1.f / 128.f) - 2.f * cr + recon;
    out[b] = fminf(fmaxf(res, 0.f), 10000.f);
  }
}

extern "C" void kernel_launch(void* const* d_in, const int* in_sizes, int n_in,
                              void* d_out, int out_size, void* d_ws, size_t ws_size,
                              hipStream_t stream) {
  const float* A      = (const float*)d_in[0];
  const float* span_t = (const float*)d_in[1];
  const float* W      = (const float*)d_in[2];
  const float* U      = (const float*)d_in[3];
  const float* PS     = (const float*)d_in[4];
  float* out = (float*)d_out;

  char* p = (char*)d_ws;
  float* mhat = (float*)p; p += (size_t)Bb * 4;
  float* SWp  = (float*)p; p += (size_t)SKW * Bb * Cc * 4;
  float* SC   = (float*)p; p += (size_t)Bb * Cc * 4;
  float* G    = (float*)p; p += (size_t)Cc * Cc * 4;
  u16*   S    = (u16*)p;   p += (size_t)Bb * Nn * 2;
  float* Au   = (float*)p; p += (size_t)Bb * Cc * Rr * 4;
  size_t fixed = (size_t)(p - (char*)d_ws);
  size_t UTsz = (size_t)Cc * Lflat * 2;                       // 67 MB
  bool planA = ws_size >= fixed + UTsz + (size_t)3 * 8 * 16384 * 4;

  topk_kernel<<<dim3(Bb), dim3(256), 0, stream>>>(A, S, mhat);
  scorew_mfma_kernel<<<dim3(4, 4, SKW), dim3(256), 0, stream>>>(A, W, SWp);

  if (planA) {
    u16* UT = (u16*)p; p += UTsz;
    size_t used = fixed + UTsz;
    int nchunks = 64;
    while (nchunks > 8 && used + (size_t)(3 * nchunks) * 16384 * 4 > ws_size) nchunks >>= 1;
    float* Gpart = (float*)p;
    u2t_kernel<<<dim3(Cc, 8), dim3(256), 0, stream>>>(U, UT);
    gram_bf16_kernel<<<dim3(3 * nchunks), dim3(256), 0, stream>>>(UT, Gpart, Lflat / nchunks);
    gram_reduce_kernel<<<dim3(48), dim3(256), 0, stream>>>(Gpart, G, nchunks);
    au_gemm_kernel<<<dim3(128, 2), dim3(256), 0, stream>>>(S, UT, Au, SC);
  } else {
    int nchunks = 64;
    while (nchunks > 8 && fixed + (size_t)(3 * nchunks) * 16384 * 4 > ws_size) nchunks >>= 1;
    float* Gpart = (float*)p;
    gram_mfma_kernel<<<dim3(3 * nchunks), dim3(256), 0, stream>>>(U, Gpart, Lflat / nchunks);
    gram_reduce_kernel<<<dim3(48), dim3(256), 0, stream>>>(Gpart, G, nchunks);
    au_mfma_kernel<<<dim3(Cc, 2), dim3(256), 0, stream>>>(U, S, Au, SC);
  }

  softfin_kernel<<<dim3(Bb), dim3(256), 0, stream>>>(SWp, SC, span_t, PS, G, Au, mhat, out);
}